// Round 1
// baseline (503.159 us; speedup 1.0000x reference)
//
#include <hip/hip_runtime.h>
#include <hip/hip_bf16.h>

typedef unsigned short u16;
typedef unsigned int   u32;
typedef __attribute__((ext_vector_type(8))) short short8;   // 8 x bf16 bits (4 VGPR)
typedef __attribute__((ext_vector_type(4))) short short4v;  // 4 x bf16 bits (8 B)
typedef __attribute__((ext_vector_type(4))) float f32x4;    // MFMA 16x16 accumulator

// round-to-nearest-even f32 -> bf16 (finite inputs only)
__device__ __forceinline__ u16 f2bf(float f) {
  u32 u = __float_as_uint(f);
  u32 r = (u + 0x7fffu + ((u >> 16) & 1u)) >> 16;
  return (u16)r;
}

// ---------------------------------------------------------------------------
// Weight pre-convert: qkv_w [768][256] fp32 -> bf16, proj_w [256][256] -> bf16
// ---------------------------------------------------------------------------
__global__ __launch_bounds__(256) void wcvt_kernel(
    const float* __restrict__ qkvw, const float* __restrict__ pw,
    u16* __restrict__ wq, u16* __restrict__ wp) {
  const int e = (blockIdx.x * 256 + threadIdx.x) * 4;  // 256 blocks -> 262144
  if (e < 196608) {
    const float4 v = *(const float4*)(qkvw + e);
    short4v o; o[0]=(short)f2bf(v.x); o[1]=(short)f2bf(v.y);
    o[2]=(short)f2bf(v.z); o[3]=(short)f2bf(v.w);
    *(short4v*)(wq + e) = o;
  } else {
    const int e2 = e - 196608;
    const float4 v = *(const float4*)(pw + e2);
    short4v o; o[0]=(short)f2bf(v.x); o[1]=(short)f2bf(v.y);
    o[2]=(short)f2bf(v.z); o[3]=(short)f2bf(v.w);
    *(short4v*)(wp + e2) = o;
  }
}

// ---------------------------------------------------------------------------
// CPB MLP: table[225][8] = relu(coords @ w1^T + b1) @ w2^T   (fp32 math)
// ---------------------------------------------------------------------------
__global__ __launch_bounds__(256) void cpb_kernel(
    const float* __restrict__ ct, const float* __restrict__ w1,
    const float* __restrict__ b1, const float* __restrict__ w2,
    float* __restrict__ table) {
  const int r = blockIdx.x;            // 0..224
  const int t = threadIdx.x;           // 0..255
  const int lane = t & 63, wave = t >> 6;
  const float c0 = ct[r * 2 + 0];
  const float c1 = ct[r * 2 + 1];
  float acc[8] = {0.f, 0.f, 0.f, 0.f, 0.f, 0.f, 0.f, 0.f};
  for (int j = t; j < 512; j += 256) {
    float hid = fmaxf(c0 * w1[j * 2] + c1 * w1[j * 2 + 1] + b1[j], 0.f);
#pragma unroll
    for (int hh = 0; hh < 8; ++hh) acc[hh] += hid * w2[hh * 512 + j];
  }
#pragma unroll
  for (int hh = 0; hh < 8; ++hh)
#pragma unroll
    for (int off = 1; off < 64; off <<= 1) acc[hh] += __shfl_xor(acc[hh], off);
  __shared__ float red[4][8];
  if (lane == 0)
#pragma unroll
    for (int hh = 0; hh < 8; ++hh) red[wave][hh] = acc[hh];
  __syncthreads();
  if (t < 8) table[r * 8 + t] = red[0][t] + red[1][t] + red[2][t] + red[3][t];
}

// bias16[h][i*64+j] = 16*sigmoid(table[rel_idx[i*64+j]][h])
__global__ __launch_bounds__(256) void gather_kernel(
    const float* __restrict__ table, const int* __restrict__ rel,
    float* __restrict__ bias16) {
  const int e = blockIdx.x * 256 + threadIdx.x;  // 8*4096 = 32768
  const int hh = e >> 12, ij = e & 4095;
  const float v = table[rel[ij] * 8 + hh];
  bias16[e] = 16.f * (1.f / (1.f + __expf(-v)));
}

// ---------------------------------------------------------------------------
// Fully fused per-window kernel: 512 threads (8 waves), one block per window.
//   A: stage x[64][256] -> bf16 LDS
//   B: QKV GEMM (wave owns 96 cols x 64 rows, K=256); epilogue does per-row
//      L2-norm of q,k IN-REGISTER (shfl over l15) and writes normalized Q,K
//      and transposed V straight into per-head LDS layouts.
//   C: wave-per-head attention: S=Qn.Kn^T (16 MFMA), softmax, P->wave-private
//      LDS, O=P.V (16 MFMA) -> o_lds.
//   D: proj GEMM from o_lds (wave owns 32 output cols), fp32 out.
// Q/K/V never touch global memory. 4 __syncthreads per block.
// LDS: sA 33792B (lA -> o), sB 73728B (qn+kn -> p), sV 36864B (vt) = 144384B
// ---------------------------------------------------------------------------
__global__ __launch_bounds__(512) void fused_kernel(
    const float* __restrict__ X,      // [131072][256] fp32
    const float* __restrict__ mask,   // [64][64][64] fp32
    const float* __restrict__ bias16, // [8][4096] fp32
    const float* __restrict__ lsc,    // [8] fp32
    const u16*  __restrict__ Wqb,     // [768][256] bf16
    const float* __restrict__ qb, const float* __restrict__ vbias,
    const u16*  __restrict__ Wpb,     // [256][256] bf16
    const float* __restrict__ pb,     // [256] fp32
    float* __restrict__ out) {        // [131072][256] fp32
  __shared__ __attribute__((aligned(16))) u16 sA[16896];  // lA[8][64][32] -> o[64][264]
  __shared__ __attribute__((aligned(16))) u16 sB[36864];  // qn[8][64][32]+kn[8][64][32] -> p[8][64][72]
  __shared__ __attribute__((aligned(16))) u16 sV[18432];  // vt[8][32][72]

  const int bw = blockIdx.x;        // window 0..2047
  const int w  = bw & 63;           // mask window index (chunks of 64)
  const int tid  = threadIdx.x;
  const int wave = tid >> 6, lane = tid & 63;
  const int l15 = lane & 15, l4 = lane >> 4;

  // ---- Phase A: stage x -> bf16 lA[kf][row][32] (coalesced, conflict-free)
  {
    const int cq  = tid & 7;        // 8 chunks of 4 fp32 per 32-col kf group
    const int rlo = tid >> 3;       // 0..63
    const float* xrow = X + ((size_t)bw * 64 + rlo) * 256;
#pragma unroll
    for (int kf = 0; kf < 8; ++kf) {
      const float4 xv = *(const float4*)(xrow + kf * 32 + cq * 4);
      short4v t4; t4[0]=(short)f2bf(xv.x); t4[1]=(short)f2bf(xv.y);
      t4[2]=(short)f2bf(xv.z); t4[3]=(short)f2bf(xv.w);
      *(short4v*)&sA[kf * 2048 + rlo * 32 + cq * 4] = t4;
    }
  }
  __syncthreads();

  // ---- Phase B: QKV GEMM: rows 0..63 x cols [wave*96, wave*96+96), K=256
  {
    f32x4 acc[4][6];
#pragma unroll
    for (int mi = 0; mi < 4; ++mi)
#pragma unroll
      for (int nj = 0; nj < 6; ++nj) acc[mi][nj] = (f32x4){0.f, 0.f, 0.f, 0.f};

#pragma unroll
    for (int kf = 0; kf < 8; ++kf) {
      short8 af[4];
#pragma unroll
      for (int mi = 0; mi < 4; ++mi)
        af[mi] = *(const short8*)&sA[kf * 2048 + (mi * 16 + l15) * 32 + l4 * 8];
#pragma unroll
      for (int nj = 0; nj < 6; ++nj) {
        const short8 bf = *(const short8*)(
            Wqb + (size_t)(wave * 96 + nj * 16 + l15) * 256 + kf * 32 + l4 * 8);
#pragma unroll
        for (int mi = 0; mi < 4; ++mi)
          acc[mi][nj] = __builtin_amdgcn_mfma_f32_16x16x32_bf16(af[mi], bf, acc[mi][nj], 0, 0, 0);
      }
    }

    // epilogue: 3 head-chunks of 32 cols each; head fully inside one wave.
#pragma unroll
    for (int t = 0; t < 3; ++t) {
      const int nbase = wave * 96 + t * 32;   // wave-uniform
      const int which = nbase >> 8;           // 0=Q 1=K 2=V
      const int h = (nbase >> 5) & 7;
      const int c = nbase & 255;
      if (which <= 1) {
        // normalize rows: 32 cols = 2 accum tiles x 16 lanes (l15)
        u16* dst = (which == 0 ? sB : sB + 16384) + h * 2048;
        const float b0 = (which == 0) ? qb[c + l15] : 0.f;
        const float b1 = (which == 0) ? qb[c + 16 + l15] : 0.f;
#pragma unroll
        for (int mi = 0; mi < 4; ++mi)
#pragma unroll
          for (int r = 0; r < 4; ++r) {
            const float v0 = acc[mi][2 * t][r] + b0;
            const float v1 = acc[mi][2 * t + 1][r] + b1;
            float ss = v0 * v0 + v1 * v1;
            ss += __shfl_xor(ss, 1); ss += __shfl_xor(ss, 2);
            ss += __shfl_xor(ss, 4); ss += __shfl_xor(ss, 8);
            const float inv = 1.f / fmaxf(sqrtf(ss), 1e-12f);
            const int m = mi * 16 + l4 * 4 + r;
            dst[m * 32 + l15]      = f2bf(v0 * inv);
            dst[m * 32 + 16 + l15] = f2bf(v1 * inv);
          }
      } else {
        // V: add bias, write transposed vt[h][d][token]
        const float b0 = vbias[c + l15];
        const float b1 = vbias[c + 16 + l15];
        u16* dst = sV + h * 2304;
#pragma unroll
        for (int mi = 0; mi < 4; ++mi)
#pragma unroll
          for (int r = 0; r < 4; ++r) {
            const int m = mi * 16 + l4 * 4 + r;
            dst[l15 * 72 + m]        = f2bf(acc[mi][2 * t][r] + b0);
            dst[(16 + l15) * 72 + m] = f2bf(acc[mi][2 * t + 1][r] + b1);
          }
      }
    }
  }
  __syncthreads();   // qn/kn/vt complete

  // ---- Phase C: attention, wave == head
  {
    const int h = wave;
    short8 aq[4], bk[4];
#pragma unroll
    for (int i = 0; i < 4; ++i)
      aq[i] = *(const short8*)&sB[h * 2048 + (i * 16 + l15) * 32 + l4 * 8];
#pragma unroll
    for (int j = 0; j < 4; ++j)
      bk[j] = *(const short8*)&sB[16384 + h * 2048 + (j * 16 + l15) * 32 + l4 * 8];

    f32x4 s[4][4];
#pragma unroll
    for (int i = 0; i < 4; ++i)
#pragma unroll
      for (int j = 0; j < 4; ++j) {
        const f32x4 z = {0.f, 0.f, 0.f, 0.f};
        s[i][j] = __builtin_amdgcn_mfma_f32_16x16x32_bf16(aq[i], bk[j], z, 0, 0, 0);
      }
    __syncthreads();   // all waves' q/k frags loaded -> sB reusable as p

    const float scale = expf(fminf(lsc[h], 4.60517018598809136804f));
    const float* brow = bias16 + h * 4096;
    const float* mrow = mask + (size_t)w * 4096;
    u16* pW = sB + wave * 4608;     // wave-private P [64][72]

#pragma unroll
    for (int i = 0; i < 4; ++i)
#pragma unroll
      for (int r = 0; r < 4; ++r) {
        const int m = i * 16 + l4 * 4 + r;
        float v0[4]; float mx = -3.0e38f;
#pragma unroll
        for (int j = 0; j < 4; ++j) {
          const int col = j * 16 + l15;
          const float sv = s[i][j][r] * scale + brow[m * 64 + col] + mrow[m * 64 + col];
          v0[j] = sv; mx = fmaxf(mx, sv);
        }
        mx = fmaxf(mx, __shfl_xor(mx, 1)); mx = fmaxf(mx, __shfl_xor(mx, 2));
        mx = fmaxf(mx, __shfl_xor(mx, 4)); mx = fmaxf(mx, __shfl_xor(mx, 8));
        float sum = 0.f;
#pragma unroll
        for (int j = 0; j < 4; ++j) { v0[j] = __expf(v0[j] - mx); sum += v0[j]; }
        sum += __shfl_xor(sum, 1); sum += __shfl_xor(sum, 2);
        sum += __shfl_xor(sum, 4); sum += __shfl_xor(sum, 8);
        const float isum = 1.f / sum;
#pragma unroll
        for (int j = 0; j < 4; ++j)
          pW[m * 72 + j * 16 + l15] = f2bf(v0[j] * isum);
      }
    // wave-internal RAW on pW ordered by lgkmcnt (proven pattern)

    // O = P @ V : 4 m-tiles x 2 d-tiles x 2 k-steps
    f32x4 oa[4][2];
#pragma unroll
    for (int i = 0; i < 4; ++i)
#pragma unroll
      for (int nb = 0; nb < 2; ++nb) oa[i][nb] = (f32x4){0.f, 0.f, 0.f, 0.f};
#pragma unroll
    for (int kb = 0; kb < 2; ++kb) {
      short8 pa[4];
#pragma unroll
      for (int i = 0; i < 4; ++i)
        pa[i] = *(const short8*)&pW[(i * 16 + l15) * 72 + kb * 32 + l4 * 8];
#pragma unroll
      for (int nb = 0; nb < 2; ++nb) {
        const short8 vb8 = *(const short8*)&sV[h * 2304 + (nb * 16 + l15) * 72 + kb * 32 + l4 * 8];
#pragma unroll
        for (int i = 0; i < 4; ++i)
          oa[i][nb] = __builtin_amdgcn_mfma_f32_16x16x32_bf16(pa[i], vb8, oa[i][nb], 0, 0, 0);
      }
    }
#pragma unroll
    for (int i = 0; i < 4; ++i)
#pragma unroll
      for (int nb = 0; nb < 2; ++nb)
#pragma unroll
        for (int r = 0; r < 4; ++r) {
          const int m = i * 16 + l4 * 4 + r;
          sA[m * 264 + h * 32 + nb * 16 + l15] = f2bf(oa[i][nb][r]);
        }
  }
  __syncthreads();   // o complete across all waves

  // ---- Phase D: proj. wave owns output cols [wave*32, wave*32+32), K=256
  {
    const int n0 = wave * 32;
    f32x4 pacc[4][2];
#pragma unroll
    for (int mi = 0; mi < 4; ++mi)
#pragma unroll
      for (int nj = 0; nj < 2; ++nj) pacc[mi][nj] = (f32x4){0.f, 0.f, 0.f, 0.f};
#pragma unroll
    for (int k0 = 0; k0 < 256; k0 += 32) {
      short8 afr[4];
#pragma unroll
      for (int mi = 0; mi < 4; ++mi)
        afr[mi] = *(const short8*)&sA[(mi * 16 + l15) * 264 + k0 + l4 * 8];
#pragma unroll
      for (int nj = 0; nj < 2; ++nj) {
        const short8 bfr = *(const short8*)(
            Wpb + (size_t)(n0 + nj * 16 + l15) * 256 + k0 + l4 * 8);
#pragma unroll
        for (int mi = 0; mi < 4; ++mi)
          pacc[mi][nj] = __builtin_amdgcn_mfma_f32_16x16x32_bf16(afr[mi], bfr, pacc[mi][nj], 0, 0, 0);
      }
    }
    float* orow = out + (size_t)bw * 64 * 256;
#pragma unroll
    for (int mi = 0; mi < 4; ++mi)
#pragma unroll
      for (int nj = 0; nj < 2; ++nj) {
        const int n = n0 + nj * 16 + l15;
        const float bias = pb[n];
#pragma unroll
        for (int r = 0; r < 4; ++r) {
          const int m = mi * 16 + l4 * 4 + r;
          orow[(size_t)m * 256 + n] = pacc[mi][nj][r] + bias;
        }
      }
  }
}

// ---------------------------------------------------------------------------
// ws layout: [0,16K) table | [16K,144K) bias16 | [256K,640K) Wqkv bf16 |
// [704K,832K) Wproj bf16.  No QKV buffers, no chunking.
// ---------------------------------------------------------------------------
extern "C" void kernel_launch(void* const* d_in, const int* in_sizes, int n_in,
                              void* d_out, int out_size, void* d_ws, size_t ws_size,
                              hipStream_t stream) {
  (void)in_sizes; (void)n_in; (void)out_size; (void)ws_size;
  const float* x    = (const float*)d_in[0];
  const float* mask = (const float*)d_in[1];
  const float* qkvw = (const float*)d_in[2];
  const float* qb   = (const float*)d_in[3];
  const float* vb   = (const float*)d_in[4];
  const float* lsc  = (const float*)d_in[5];
  const float* w1   = (const float*)d_in[6];
  const float* b1   = (const float*)d_in[7];
  const float* w2   = (const float*)d_in[8];
  const float* pw   = (const float*)d_in[9];
  const float* pb   = (const float*)d_in[10];
  const float* ct   = (const float*)d_in[11];
  const int* rel    = (const int*)d_in[12];
  float* out = (float*)d_out;

  char* ws = (char*)d_ws;
  float* table  = (float*)(ws);
  float* bias16 = (float*)(ws + 16384);
  u16* Wqb = (u16*)(ws + 262144);   // 393,216 B
  u16* Wpb = (u16*)(ws + 720896);   // 131,072 B

  wcvt_kernel<<<256, 256, 0, stream>>>(qkvw, pw, Wqb, Wpb);
  cpb_kernel<<<225, 256, 0, stream>>>(ct, w1, b1, w2, table);
  gather_kernel<<<128, 256, 0, stream>>>(table, rel, bias16);
  fused_kernel<<<2048, 512, 0, stream>>>(x, mask, bias16, lsc, Wqb, qb, vb,
                                         Wpb, pb, out);
}